// Round 12
// baseline (291.051 us; speedup 1.0000x reference)
//
#include <hip/hip_runtime.h>
#include <hip/hip_bf16.h>
#include <math.h>

// Cart2Polar: output[b,c,y,x] = bilinear_sample(grid_feat[b,c], gx(y,x), gy(y,x))
// ref_feat is fully overwritten by the reference's scatter -> unused.
// Shapes (fixed): grid_feat [4,64,480,480] f32, out [4,64,480,360] f32.
//
// R12: gather->stream conversion. R9-R11 proved the wall is the per-CU
// vector-memory line-request path (MLP-forcing null, locality null/negative,
// all pipes idle): wave64 gathers splinter into ~15-30 L1-missing line
// requests each. New structure: tall-thin 32r x 8theta tiles whose cartesian
// footprint fits a 40x40 window (proven: radial span 15.4px + arc 29.3px
// -> bbox <= 36 +2 bilinear). Stage the window per channel with COALESCED
// loads into double-buffered LDS, bilinear-sample from LDS, accumulate in
// regs (full unroll), store all channels at the end (no per-channel store
// drain at barriers).

#define BB 4
#define CC 64
#define HC 480
#define WC 480
#define HP 480
#define WP 360

#define TY 32                  // radii per tile
#define TX 8                   // thetas per tile  (360/8=45 exact, no tail)
#define BYT (HP / TY)          // 15
#define BXT (WP / TX)          // 45
#define CSPLIT 2
#define CCB (CC / CSPLIT)      // 32 channels per block
#define NWG (BB * BYT * BXT * CSPLIT)  // 5400

#define WIN 40                 // staging window rows/cols bound
#define WSTR 41                // padded LDS row stride
#define NSLOT (WIN * WSTR)     // 1640 valid slots
#define LDSZ (NSLOT + 1)       // +1 dump slot
#define NIT 7                  // ceil(40*40/256)

__global__ __launch_bounds__(256, 4) void c2p_kernel(const float* __restrict__ g,
                                                     float* __restrict__ out) {
    __shared__ float sbuf[2][LDSZ];
    __shared__ int red[2][4];

    // identity dispatch (R8: round-robin XCD mixes radii -> balance)
    const int logical = blockIdx.x;
    const int h  = logical & (CSPLIT - 1);
    const int t1 = logical >> 1;
    const int xt = t1 % BXT;
    const int t2 = t1 / BXT;
    const int yt = t2 % BYT;
    const int b  = t2 / BYT;

    const int tid  = threadIdx.x;
    const int lane = tid & 63;
    const int w    = tid >> 6;
    const int orow = tid >> 3;            // 0..31 radius index in tile
    const int ocol = tid & 7;             // 0..7  theta index in tile
    const int y = yt * TY + orow;
    const int x = xt * TX + ocol;

    // polar grid math (matches reference, fp32)
    const float PI = 3.14159265358979323846f;
    float theta = PI - (float)x * (2.0f * PI / (float)WP);
    float r = ((float)HP - 0.5f - (float)y + 3.0f) * (1.0f / ((float)HP + 3.0f)) * ((float)WC * 0.5f);
    float sn, cs;
    __sincosf(theta, &sn, &cs);
    float index_x = r * cs + (float)WC * 0.5f;
    float index_y = r * sn + (float)WC * 0.5f;
    const float scale = (float)(WC - 1) / (float)WC;
    float gx = index_x * scale;
    float gy = index_y * scale;

    float x0f = floorf(gx);
    float y0f = floorf(gy);
    float wx1 = gx - x0f;
    float wy1 = gy - y0f;
    float wx0 = 1.0f - wx1;
    float wy0 = 1.0f - wy1;

    // proven in-bounds: x0,y0 in [0,478] -> no clamp, no zero-padding
    const int x0 = (int)x0f;
    const int y0 = (int)y0f;

    const float w00 = wx0 * wy0;
    const float w10 = wx1 * wy0;
    const float w01 = wx0 * wy1;
    const float w11 = wx1 * wy1;

    // ---- block-wide min reduce for window anchor (max proven to fit WIN) ----
    int lo_y = y0, lo_x = x0;
#pragma unroll
    for (int off = 32; off; off >>= 1) {
        lo_y = min(lo_y, __shfl_xor(lo_y, off));
        lo_x = min(lo_x, __shfl_xor(lo_x, off));
    }
    if (lane == 0) { red[0][w] = lo_y; red[1][w] = lo_x; }
    __syncthreads();
    const int ymin = min(min(red[0][0], red[0][1]), min(red[0][2], red[0][3]));
    const int xmin = min(min(red[1][0], red[1][1]), min(red[1][2], red[1][3]));

    // ---- precompute staging slots (channel-independent) ----
    int voff[NIT], loff[NIT];
#pragma unroll
    for (int k = 0; k < NIT; ++k) {
        const int idx = tid + 256 * k;
        const int row = (idx * 1639) >> 16;        // == idx/40 for idx<2730
        const int col = idx - row * 40;
        const int gyc = min(ymin + row, HC - 1);   // clamp: garbage-safe
        const int gxc = min(xmin + col, WC - 1);
        voff[k] = (gyc * WC + gxc) * 4;            // byte offset, 32-bit
        loff[k] = (idx < WIN * WIN) ? (idx + row) : NSLOT;  // row*41+col == idx+row
    }

    constexpr int HWc = HC * WC;
    constexpr int HWp = HP * WP;
    const float* __restrict__ base = g + ((size_t)b * CC + (size_t)h * CCB) * HWc;
    float* __restrict__ ob = out + ((size_t)b * CC + (size_t)h * CCB) * HWp
                                 + (size_t)y * WP + x;
    const int sidx = (y0 - ymin) * WSTR + (x0 - xmin);   // <= 38*41+38, +42 fits

    float v[CCB];
    float st[NIT];

    // ---- prologue: stage channel 0 into sbuf[0] ----
    {
        const float* gch = base;
#pragma unroll
        for (int k = 0; k < NIT; ++k)
            asm volatile("global_load_dword %0, %1, %2"
                         : "=v"(st[k]) : "v"(voff[k]), "s"(gch));
        asm volatile("s_waitcnt vmcnt(0)" ::: "memory");
        __builtin_amdgcn_sched_barrier(0);
#pragma unroll
        for (int k = 0; k < NIT; ++k) sbuf[0][loff[k]] = st[k];
        __syncthreads();
    }

    // ---- main loop: sample ch j from sbuf[p] while staging ch j+1 ----
#pragma unroll
    for (int j = 0; j < CCB; ++j) {
        const int p = j & 1;
        if (j + 1 < CCB) {
            const float* gch = base + (size_t)(j + 1) * HWc;
#pragma unroll
            for (int k = 0; k < NIT; ++k)
                asm volatile("global_load_dword %0, %1, %2"
                             : "=v"(st[k]) : "v"(voff[k]), "s"(gch));
        }
        // bilinear from LDS
        const float* __restrict__ sb = sbuf[p];
        const float s00 = sb[sidx];
        const float s10 = sb[sidx + 1];
        const float s01 = sb[sidx + WSTR];
        const float s11 = sb[sidx + WSTR + 1];
        v[j] = s00 * w00 + s10 * w10 + s01 * w01 + s11 * w11;

        if (j + 1 < CCB) {
            asm volatile("s_waitcnt vmcnt(0)" ::: "memory");
            __builtin_amdgcn_sched_barrier(0);
#pragma unroll
            for (int k = 0; k < NIT; ++k) sbuf[p ^ 1][loff[k]] = st[k];
        }
        __syncthreads();
    }

    // ---- epilogue: store all channels (no per-channel store drain) ----
#pragma unroll
    for (int j = 0; j < CCB; ++j)
        __builtin_nontemporal_store(v[j], &ob[(size_t)j * HWp]);
}

extern "C" void kernel_launch(void* const* d_in, const int* in_sizes, int n_in,
                              void* d_out, int out_size, void* d_ws, size_t ws_size,
                              hipStream_t stream) {
    const float* grid_feat = (const float*)d_in[0];
    float* out = (float*)d_out;
    c2p_kernel<<<NWG, 256, 0, stream>>>(grid_feat, out);
}

// Round 13
// 118.933 us; speedup vs baseline: 2.4472x; 2.4472x over previous
//
#include <hip/hip_runtime.h>
#include <hip/hip_bf16.h>
#include <math.h>

// Cart2Polar: output[b,c,y,x] = bilinear_sample(grid_feat[b,c], gx(y,x), gy(y,x))
// ref_feat is fully overwritten by the reference's scatter -> unused.
// Shapes (fixed): grid_feat [4,64,480,480] f32, out [4,64,480,360] f32.
//
// R13 = R10 (best: bench 131.9) with CSPLIT=8. Evidence ledger:
//  - lines/instr reduction (R4): 1.7x win -> wall is line-request processing
//  - address halving (R6): +7% only; MLP forcing (R9/R10): null
//  - locality improvement (R11): FETCH down, dur UP -> not HBM/L3-bound
//  - LDS window staging (R12): 4.6x traffic amplification, regression
//  - CSPLIT 2->4 (R9): bench 144->133 (TLP helps bench-time tail/latency)
// => keep R10 gather geometry (16y x 4x wave, paired dwordx2, LDS-transposed
//    64B stores), push TLP once more: 8 ch/block, 22080 blocks, 8 blocks/CU.

#define BB 4
#define CC 64
#define HC 480
#define WC 480
#define HP 480
#define WP 360

#define TY 16
#define TX 16
#define BYT (HP / TY)                  // 30
#define BXT ((WP + TX - 1) / TX)       // 23 (last tile x>=360 lanes: computed, not stored)
#define CSPLIT 8
#define CCB (CC / CSPLIT)              // 8 channels per block
#define NWG (BB * BYT * BXT * CSPLIT)  // 22080
#define CB 8                           // = CCB, single LDS batch

typedef float f2a __attribute__((ext_vector_type(2), aligned(8)));

__global__ __launch_bounds__(256, 2) void c2p_kernel(const float* __restrict__ g,
                                                     float* __restrict__ out) {
    __shared__ float lds[CB][TY][TX + 1];   // +1 pad: conflict-free scalar r/w

    // identity mapping: round-robin over XCDs mixes radii (load balance, R8 win)
    const int logical = blockIdx.x;
    const int h  = logical & (CSPLIT - 1);
    const int t1 = logical >> 3;
    const int xt = t1 % BXT;
    const int t2 = t1 / BXT;
    const int yt = t2 % BYT;
    const int b  = t2 / BYT;

    const int tid  = threadIdx.x;
    const int lane = tid & 63;
    const int w    = tid >> 6;
    // gather-phase mapping: wave = 16 consecutive y (radii) x 4 consecutive x
    const int ly = lane >> 2;                 // 0..15
    const int lx = (w << 2) | (lane & 3);     // 0..15
    const int y  = yt * TY + ly;
    const int x  = xt * TX + lx;              // may be >=360 in last tile (not stored)

    // polar grid math (matches reference, fp32)
    const float PI = 3.14159265358979323846f;
    float theta = PI - (float)x * (2.0f * PI / (float)WP);
    float r = ((float)HP - 0.5f - (float)y + 3.0f) * (1.0f / ((float)HP + 3.0f)) * ((float)WC * 0.5f);
    float s, c;
    __sincosf(theta, &s, &c);
    float index_x = r * c + (float)WC * 0.5f;
    float index_y = r * s + (float)WC * 0.5f;
    const float scale = (float)(WC - 1) / (float)WC;
    float gx = index_x * scale;
    float gy = index_y * scale;

    float x0f = floorf(gx);
    float y0f = floorf(gy);
    float wx1 = gx - x0f;
    float wy1 = gy - y0f;
    float wx0 = 1.0f - wx1;
    float wy0 = 1.0f - wy1;

    // proven in-bounds for this geometry: x0,y0 in [0,478] -> no clamp/validity
    const int x0 = (int)x0f;
    const int y0 = (int)y0f;

    const float w00 = wx0 * wy0;
    const float w10 = wx1 * wy0;
    const float w01 = wx0 * wy1;
    const float w11 = wx1 * wy1;

    const int o0 = y0 * WC + x0;     // row y0, cols (x0, x0+1) as one float2
    const int o1 = o0 + WC;          // row y0+1

    constexpr int HWc = HC * WC;
    constexpr int HWp = HP * WP;

    const float* __restrict__ base = g + ((size_t)b * CC + h * CCB) * HWc;

    // store-phase mapping: x-major, 16 rows x 64B per wave-store
    const int srow = tid >> 4;                // 0..15
    const int scol = tid & 15;                // 0..15
    const int sy = yt * TY + srow;
    const int sx = xt * TX + scol;
    const bool sok = (sx < WP);
    float* __restrict__ ob = out + ((size_t)b * CC + h * CCB) * HWp + (size_t)sy * WP + sx;

    // ---- asm-forced gather cluster: 16 dwordx2 loads, all in flight ----
    f2a a0[CB], a1[CB];
#pragma unroll
    for (int j = 0; j < CB; ++j) {
        const float* p0 = base + (size_t)j * HWc + o0;
        const float* p1 = base + (size_t)j * HWc + o1;
        asm volatile("global_load_dwordx2 %0, %1, off"
                     : "=v"(a0[j]) : "v"(p0));
        asm volatile("global_load_dwordx2 %0, %1, off"
                     : "=v"(a1[j]) : "v"(p1));
    }

    // ---- counted drain: consume channel j while 2*(CB-1-j) loads still fly ----
#pragma unroll
    for (int j = 0; j < CB; ++j) {
        asm volatile("s_waitcnt vmcnt(%0)" :: "i"(2 * (CB - 1 - j)) : "memory");
        __builtin_amdgcn_sched_barrier(0);
        lds[j][ly][lx] = a0[j].x * w00 + a0[j].y * w10
                       + a1[j].x * w01 + a1[j].y * w11;
    }
    __syncthreads();

    if (sok) {
#pragma unroll
        for (int j = 0; j < CB; ++j)
            __builtin_nontemporal_store(lds[j][srow][scol], &ob[(size_t)j * HWp]);
    }
}

extern "C" void kernel_launch(void* const* d_in, const int* in_sizes, int n_in,
                              void* d_out, int out_size, void* d_ws, size_t ws_size,
                              hipStream_t stream) {
    const float* grid_feat = (const float*)d_in[0];
    float* out = (float*)d_out;
    c2p_kernel<<<NWG, 256, 0, stream>>>(grid_feat, out);
}